// Round 12
// baseline (380.804 us; speedup 1.0000x reference)
//
#include <hip/hip_runtime.h>
#include <hip/hip_bf16.h>

#define B_ 32
#define T_ 4096
#define H_ 512
#define A_ 512
#define C_ 32
#define KTOT 544            // H + C (conv folded in as K-extension)
#define NKS  (KTOT / 32)    // 17 MFMA k-steps
#define TT   64             // t-tile rows per block

typedef float f32x4 __attribute__((ext_vector_type(4)));
typedef __bf16 bf16x8 __attribute__((ext_vector_type(8)));

__device__ inline float fast_tanh(float x) {
    // tanh(x) = 1 - 2/(exp(2x)+1); exact at saturation, |err| ~1e-7
    float t = __expf(2.0f * x);
    return 1.0f - 2.0f / (t + 1.0f);
}

__device__ __forceinline__ void async16(const void* g, void* l) {
    __builtin_amdgcn_global_load_lds(
        (const __attribute__((address_space(1))) unsigned int*)g,
        (__attribute__((address_space(3))) unsigned int*)l, 16, 0, 0);
}

// ---------------- prep: dpb = dec@W^T + b ; V,U -> unified bf16 fragment buffer ----
__global__ __launch_bounds__(256) void prep_kernel(
    const float* __restrict__ dec, const float* __restrict__ W,
    const float* __restrict__ bvec, const float* __restrict__ V,
    const float* __restrict__ U,
    float* __restrict__ dpb, __bf16* __restrict__ Vsall) {
    int id = blockIdx.x * 256 + threadIdx.x;
    const int N1 = B_ * A_;          // 16384
    const int N2 = A_ * H_;          // 262144
    if (id < N1) {
        int b = id / A_, a = id % A_;
        const float* dr = dec + b * H_;
        const float* wr = W + (size_t)a * H_;
        float s = 0.f;
        #pragma unroll 8
        for (int h = 0; h < H_; ++h) s += dr[h] * wr[h];
        dpb[id] = s + bvec[a];
    } else if (id < N1 + N2) {
        int e = id - N1;
        int a = e >> 9, k = e & 511;
        Vsall[((k >> 3) * A_ + a) * 8 + (k & 7)] = (__bf16)V[(size_t)a * H_ + k];
    } else {
        int e = id - N1 - N2;        // 16384 U elements
        int a = e >> 5, c = e & 31;
        int k = H_ + c;
        Vsall[((k >> 3) * A_ + a) * 8 + (k & 7)] = (__bf16)U[a * C_ + c];
    }
}

// ---------------- ablation-instrumented scores (r8 structure, V=1 is the real one) ----
// V=1: full.  V=2: A-path (enc load+cvt+ds_write) removed.  V=3: B async-stage removed.
template<int V>
__global__ __launch_bounds__(512) void scores_abl(
    const float* __restrict__ enc, const float* __restrict__ align,
    const float* __restrict__ conv_w, const float* __restrict__ conv_b,
    const __bf16* __restrict__ Vsall, const float* __restrict__ dpb,
    const float* __restrict__ wvec, float* __restrict__ sout) {
    constexpr bool DO_A = (V != 2);
    constexpr bool DO_B = (V != 3);
    const int t0 = blockIdx.x * TT;
    const int b  = blockIdx.y;
    const int tid = threadIdx.x;
    const int lane = tid & 63, wid = tid >> 6;
    const int row0 = lane & 15;   // C/D col lane
    const int kg   = lane >> 4;   // k-group 0..3 within the 32-k step
    const int wq   = wid & 3;     // col quarter
    const int wr   = wid >> 2;    // row half (32 rows)
    const int wcol = wq * 128;

    __shared__ char smem[73728];  // A dbuf 2x4KB @0, B dbuf 2x32KB @8192
    float* spart = (float*)smem;  // [4][TT] = 1KB, aliases A after the loop

    const float* encb = enc + ((size_t)b * T_ + t0) * H_;
    const int arow = tid >> 2, akgl = tid & 3;   // A staging assignment (tid<256)

    // ---- stage kstep 0 ----
    if constexpr (DO_B) {
        __bf16* bdst = (__bf16*)(smem + 8192);
        #pragma unroll
        for (int i = 0; i < 4; ++i) {
            int u = i * 512 + tid;
            async16(Vsall + u * 8, bdst + u * 8);
        }
    }
    if constexpr (DO_A) {
        if (tid < 256) {
            const float* p = encb + arow * H_ + akgl * 8;
            f32x4 lo = *reinterpret_cast<const f32x4*>(p);
            f32x4 hi = *reinterpret_cast<const f32x4*>(p + 4);
            bf16x8 v;
            v[0] = (__bf16)lo.x; v[1] = (__bf16)lo.y; v[2] = (__bf16)lo.z; v[3] = (__bf16)lo.w;
            v[4] = (__bf16)hi.x; v[5] = (__bf16)hi.y; v[6] = (__bf16)hi.z; v[7] = (__bf16)hi.w;
            int g = tid ^ ((tid >> 4) & 7);
            *reinterpret_cast<bf16x8*>((__bf16*)smem + g * 8) = v;
        }
    }
    __syncthreads();

    f32x4 acc[2][8];
    #pragma unroll
    for (int m = 0; m < 2; ++m)
        #pragma unroll
        for (int n = 0; n < 8; ++n) acc[m][n] = (f32x4){0.f, 0.f, 0.f, 0.f};

    int cur = 0;
    for (int ks = 0; ks < NKS; ++ks) {
        __bf16* Acur = (__bf16*)(smem + (cur ? 4096 : 0));
        __bf16* Anxt = (__bf16*)(smem + (cur ? 0 : 4096));
        __bf16* Bcur = (__bf16*)(smem + 8192 + (cur ? 32768 : 0));
        __bf16* Bnxt = (__bf16*)(smem + 8192 + (cur ? 0 : 32768));

        f32x4 alo, ahi;
        bool stage = (ks + 1 < NKS);
        bool conv_step = (ks + 1 == NKS - 1);
        if (stage) {
            if constexpr (DO_B) {
                const __bf16* vchunk = Vsall + (size_t)(ks + 1) * (4 * A_ * 8);
                #pragma unroll
                for (int i = 0; i < 4; ++i) {
                    int u = i * 512 + tid;
                    async16(vchunk + u * 8, Bnxt + u * 8);
                }
            }
            if constexpr (DO_A) {
                if (tid < 256 && !conv_step) {
                    const float* p = encb + arow * H_ + (ks + 1) * 32 + akgl * 8;
                    alo = *reinterpret_cast<const f32x4*>(p);
                    ahi = *reinterpret_cast<const f32x4*>(p + 4);
                }
            }
        }

        // ---- compute current k-step (identical in all variants) ----
        bf16x8 afrag[2];
        #pragma unroll
        for (int m = 0; m < 2; ++m) {
            int row = wr * 32 + m * 16 + row0;
            int u = row * 4 + kg;
            int g = u ^ ((u >> 4) & 7);
            afrag[m] = *reinterpret_cast<const bf16x8*>(Acur + g * 8);
        }
        const __bf16* bp = Bcur + kg * (A_ * 8);
        #pragma unroll
        for (int n = 0; n < 8; ++n) {
            bf16x8 bfrag = *reinterpret_cast<const bf16x8*>(bp + (wcol + n * 16 + row0) * 8);
            acc[0][n] = __builtin_amdgcn_mfma_f32_16x16x32_bf16(afrag[0], bfrag, acc[0][n], 0, 0, 0);
            acc[1][n] = __builtin_amdgcn_mfma_f32_16x16x32_bf16(afrag[1], bfrag, acc[1][n], 0, 0, 0);
        }

        // ---- write A-next to LDS ----
        if constexpr (DO_A) {
            if (stage && tid < 256) {
                bf16x8 v;
                if (!conv_step) {
                    v[0] = (__bf16)alo.x; v[1] = (__bf16)alo.y; v[2] = (__bf16)alo.z; v[3] = (__bf16)alo.w;
                    v[4] = (__bf16)ahi.x; v[5] = (__bf16)ahi.y; v[6] = (__bf16)ahi.z; v[7] = (__bf16)ahi.w;
                } else {
                    int t = t0 + arow;
                    float x0 = (t > 0) ? align[b * T_ + t - 1] : 0.f;
                    float x1 = align[b * T_ + t];
                    float x2 = (t + 1 < T_) ? align[b * T_ + t + 1] : 0.f;
                    #pragma unroll
                    for (int e = 0; e < 8; ++e) {
                        int c = akgl * 8 + e;
                        v[e] = (__bf16)(conv_b[c] + conv_w[c * 3 + 0] * x0
                                      + conv_w[c * 3 + 1] * x1 + conv_w[c * 3 + 2] * x2);
                    }
                }
                int g = tid ^ ((tid >> 4) & 7);
                *reinterpret_cast<bf16x8*>(Anxt + g * 8) = v;
            }
        }
        __syncthreads();   // identical sync structure in all variants
        cur ^= 1;
    }

    // ---- epilogue: tanh(acc + dpb)*w, reduce over A (identical) ----
    float dval[8], wv[8];
    #pragma unroll
    for (int n = 0; n < 8; ++n) {
        int a = wcol + n * 16 + row0;
        dval[n] = dpb[b * A_ + a];
        wv[n]   = wvec[a];
    }
    #pragma unroll
    for (int m = 0; m < 2; ++m) {
        float rs[4] = {0.f, 0.f, 0.f, 0.f};
        #pragma unroll
        for (int n = 0; n < 8; ++n) {
            #pragma unroll
            for (int j = 0; j < 4; ++j) {
                float x = acc[m][n][j] + dval[n];
                rs[j] += fast_tanh(x) * wv[n];
            }
        }
        #pragma unroll
        for (int j = 0; j < 4; ++j) {
            float v = rs[j];
            v += __shfl_xor(v, 1);
            v += __shfl_xor(v, 2);
            v += __shfl_xor(v, 4);
            v += __shfl_xor(v, 8);
            if (row0 == 0) spart[wq * TT + wr * 32 + m * 16 + kg * 4 + j] = v;
        }
    }
    __syncthreads();
    if (tid < TT) {
        float s = spart[0 * TT + tid] + spart[1 * TT + tid]
                + spart[2 * TT + tid] + spart[3 * TT + tid];
        sout[b * T_ + t0 + tid] = s;
    }
}

// ---------------- softmax over T per batch; fp32 alignment into d_out ----------------
__global__ __launch_bounds__(256) void softmax_k(
    const float* __restrict__ scores, float* __restrict__ out_align) {
    int b = blockIdx.x;
    int tid = threadIdx.x;
    __shared__ float redm[4];
    __shared__ float reds[4];
    float local[16];
    float mx = -1e30f;
    #pragma unroll
    for (int i = 0; i < 16; ++i) {
        float s = scores[b * T_ + tid + i * 256];
        local[i] = s;
        mx = fmaxf(mx, s);
    }
    for (int off = 32; off >= 1; off >>= 1) mx = fmaxf(mx, __shfl_xor(mx, off));
    if ((tid & 63) == 0) redm[tid >> 6] = mx;
    __syncthreads();
    mx = fmaxf(fmaxf(redm[0], redm[1]), fmaxf(redm[2], redm[3]));
    float sum = 0.f;
    #pragma unroll
    for (int i = 0; i < 16; ++i) { local[i] = __expf(local[i] - mx); sum += local[i]; }
    for (int off = 32; off >= 1; off >>= 1) sum += __shfl_xor(sum, off);
    if ((tid & 63) == 0) reds[tid >> 6] = sum;
    __syncthreads();
    sum = reds[0] + reds[1] + reds[2] + reds[3];
    float inv = 1.0f / sum;
    #pragma unroll
    for (int i = 0; i < 16; ++i)
        out_align[b * T_ + tid + i * 256] = local[i] * inv;
}

// ---------------- pout[b,chunk,h] = sum_{t in chunk} alpha * enc ----------------
__global__ __launch_bounds__(512) void pout_k(
    const float* __restrict__ enc, const float* __restrict__ alpha,
    float* __restrict__ pout) {
    int chunk = blockIdx.x;   // 0..7 (512 rows each)
    int b = blockIdx.y;
    int tid = threadIdx.x;
    int t0 = chunk * 512;
    __shared__ float as[512];
    as[tid] = alpha[b * T_ + t0 + tid];
    __syncthreads();
    float acc = 0.f;
    const float* ep = enc + ((size_t)b * T_ + t0) * H_ + tid;
    #pragma unroll 4
    for (int t = 0; t < 512; ++t) acc += as[t] * ep[(size_t)t * H_];
    pout[((size_t)b * 8 + chunk) * H_ + tid] = acc;
}

__global__ __launch_bounds__(512) void combine_k(
    const float* __restrict__ pout, float* __restrict__ out) {
    int b = blockIdx.x; int h = threadIdx.x;
    float s = 0.f;
    #pragma unroll
    for (int c = 0; c < 8; ++c) s += pout[((size_t)b * 8 + c) * H_ + h];
    out[b * H_ + h] = s;
}

extern "C" void kernel_launch(void* const* d_in, const int* in_sizes, int n_in,
                              void* d_out, int out_size, void* d_ws, size_t ws_size,
                              hipStream_t stream) {
    const float* dec    = (const float*)d_in[0];
    const float* enc    = (const float*)d_in[1];
    const float* align  = (const float*)d_in[2];
    const float* conv_w = (const float*)d_in[3];
    const float* conv_b = (const float*)d_in[4];
    const float* W      = (const float*)d_in[5];
    const float* V      = (const float*)d_in[6];
    const float* U      = (const float*)d_in[7];
    const float* bvec   = (const float*)d_in[8];
    const float* wvec   = (const float*)d_in[9];
    float* out       = (float*)d_out;           // output[B,H] fp32
    float* out_align = out + B_ * H_;           // alignment[B,T] fp32

    char* ws = (char*)d_ws;
    float*  dpb    = (float*)(ws);                   // 64 KB
    float*  scores = (float*)(ws + (64 << 10));      // 512 KB
    float*  pout   = (float*)(ws + (576 << 10));     // 512 KB
    __bf16* Vsall  = (__bf16*)(ws + (1088 << 10));   // 544 KB
    float*  dummy  = (float*)(ws + (1632 << 10));    // 512 KB (ablation sink)

    prep_kernel<<<(B_ * A_ + A_ * H_ + A_ * C_) / 256, 256, 0, stream>>>(
        dec, W, bvec, V, U, dpb, Vsall);
    // ablation probes (full grid, dummy output) — diagnostic only
    scores_abl<2><<<dim3(T_ / TT, B_), 512, 0, stream>>>(enc, align, conv_w, conv_b,
                                                         Vsall, dpb, wvec, dummy);
    scores_abl<3><<<dim3(T_ / TT, B_), 512, 0, stream>>>(enc, align, conv_w, conv_b,
                                                         Vsall, dpb, wvec, dummy);
    // the real one
    scores_abl<1><<<dim3(T_ / TT, B_), 512, 0, stream>>>(enc, align, conv_w, conv_b,
                                                         Vsall, dpb, wvec, scores);
    softmax_k<<<B_, 256, 0, stream>>>(scores, out_align);
    pout_k<<<dim3(8, B_), 512, 0, stream>>>(enc, out_align, pout);
    combine_k<<<B_, 512, 0, stream>>>(pout, out);
}

// Round 13
// 230.464 us; speedup vs baseline: 1.6523x; 1.6523x over previous
//
#include <hip/hip_runtime.h>
#include <hip/hip_bf16.h>

#define B_ 32
#define T_ 4096
#define H_ 512
#define A_ 512
#define C_ 32
#define KTOT 544            // H + C (conv folded in as K-extension)
#define NKS  (KTOT / 32)    // 17 MFMA k-steps
#define TT   64             // t-tile rows per block

typedef float f32x4 __attribute__((ext_vector_type(4)));
typedef __bf16 bf16x8 __attribute__((ext_vector_type(8)));

__device__ inline float fast_tanh(float x) {
    // tanh(x) = 1 - 2/(exp(2x)+1); exact at saturation, |err| ~1e-7
    float t = __expf(2.0f * x);
    return 1.0f - 2.0f / (t + 1.0f);
}

__device__ __forceinline__ void async16(const void* g, void* l) {
    __builtin_amdgcn_global_load_lds(
        (const __attribute__((address_space(1))) unsigned int*)g,
        (__attribute__((address_space(3))) unsigned int*)l, 16, 0, 0);
}

// ---------------- prep: dpb = dec@W^T + b ; V,U -> unified bf16 fragment buffer ----
// Vsall[(k>>3)*A + a]*8 + (k&7), k in [0,544). Per-kstep 32KB chunk contiguous.
__global__ __launch_bounds__(256) void prep_kernel(
    const float* __restrict__ dec, const float* __restrict__ W,
    const float* __restrict__ bvec, const float* __restrict__ V,
    const float* __restrict__ U,
    float* __restrict__ dpb, __bf16* __restrict__ Vsall) {
    int id = blockIdx.x * 256 + threadIdx.x;
    const int N1 = B_ * A_;          // 16384
    const int N2 = A_ * H_;          // 262144
    if (id < N1) {
        int b = id / A_, a = id % A_;
        const float* dr = dec + b * H_;
        const float* wr = W + (size_t)a * H_;
        float s = 0.f;
        #pragma unroll 8
        for (int h = 0; h < H_; ++h) s += dr[h] * wr[h];
        dpb[id] = s + bvec[a];
    } else if (id < N1 + N2) {
        int e = id - N1;
        int a = e >> 9, k = e & 511;
        Vsall[((k >> 3) * A_ + a) * 8 + (k & 7)] = (__bf16)V[(size_t)a * H_ + k];
    } else {
        int e = id - N1 - N2;        // 16384 U elements
        int a = e >> 5, c = e & 31;
        int k = H_ + c;
        Vsall[((k >> 3) * A_ + a) * 8 + (k & 7)] = (__bf16)U[a * C_ + c];
    }
}

// ---------------- fused scores: producer/consumer wave specialization ----------------
// 768 threads: wid 0..7 = consumers (64x64 output tile each: 4 A + 4 B ds_read, 16 MFMA);
//              wid 8..11 = producers (256 thr): B via async16 3-buf 2-ahead (vmcnt ledger),
//              A via 2-ahead reg prefetch -> cvt -> swizzled ds_write into 2-buf.
__global__ __launch_bounds__(768) void scores_mfma(
    const float* __restrict__ enc, const float* __restrict__ align,
    const float* __restrict__ conv_w, const float* __restrict__ conv_b,
    const __bf16* __restrict__ Vsall, const float* __restrict__ dpb,
    const float* __restrict__ wvec, float* __restrict__ scores) {
    const int t0 = blockIdx.x * TT;
    const int b  = blockIdx.y;
    const int tid = threadIdx.x;
    const int lane = tid & 63, wid = tid >> 6;
    const int row0 = lane & 15;   // C/D col lane; A-frag row lane
    const int kg   = lane >> 4;   // k-group 0..3
    const bool is_consumer = (wid < 8);
    const int ptid = tid - 512;   // producer-local id, valid when wid>=8

    // LDS: A dbuf 2x4KB @0; B 3x32KB @8192; spart aliases A after loop
    __shared__ char smem[8192 + 3 * 32768];
    float* spart = (float*)smem;   // [8][64]

    const float* encb = enc + ((size_t)b * T_ + t0) * H_;

    // producer A assignment: unit u = row*4 + kq  (row = ptid>>2, kq = ptid&3)
    const int arow = (tid - 512) >> 2;
    const int akq  = tid & 3;
    const int ag   = ((tid - 512) ^ (((tid - 512) >> 4) & 7));  // swizzled unit
    // consumer A read offsets (m = 0..3)
    int arbyte[4];
    #pragma unroll
    for (int m = 0; m < 4; ++m) {
        int row = m * 16 + row0;
        int u = row * 4 + kg;
        int g = u ^ ((u >> 4) & 7);
        arbyte[m] = g * 16;
    }
    // consumer B read base: byte = (kg*512 + wid*64 + n*16 + row0) * 16
    const int brbase = (kg * 512 + wid * 64 + row0) * 16;

    f32x4 areg[2];
    float cx0 = 0.f, cx1 = 0.f, cx2 = 0.f;

    // ---------------- prologue (producers stage kstep 0 and 1) ----------------
    if (!is_consumer) {
        #pragma unroll
        for (int s = 0; s < 2; ++s) {
            char* bdst = smem + 8192 + s * 32768;
            const __bf16* src = Vsall + (size_t)s * 16384;
            #pragma unroll
            for (int i = 0; i < 8; ++i) {
                int u = i * 256 + ptid;
                async16(src + (size_t)u * 8, bdst + u * 16);
            }
        }
        // A(0): load + cvt + write; A(1): regs
        const float* p0 = encb + (size_t)arow * H_ + akq * 8;
        f32x4 lo = *reinterpret_cast<const f32x4*>(p0);
        f32x4 hi = *reinterpret_cast<const f32x4*>(p0 + 4);
        areg[1] = *reinterpret_cast<const f32x4*>(p0 + 32);  // first half of A(1)
        // note: A units are 8 bf16 = one bf16x8 per thread; need both halves for A(1):
        // handled by reloading in-loop path (iter -1 equivalent): store second half now
        bf16x8 v;
        v[0]=(__bf16)lo.x; v[1]=(__bf16)lo.y; v[2]=(__bf16)lo.z; v[3]=(__bf16)lo.w;
        v[4]=(__bf16)hi.x; v[5]=(__bf16)hi.y; v[6]=(__bf16)hi.z; v[7]=(__bf16)hi.w;
        *reinterpret_cast<bf16x8*>(smem + ag * 16) = v;
    }
    // A(1) second half handled uniformly: producers also prefetch it
    f32x4 areg1b;
    if (!is_consumer) {
        const float* p1 = encb + (size_t)arow * H_ + 32 + akq * 8;
        areg[1] = *reinterpret_cast<const f32x4*>(p1);
        areg1b  = *reinterpret_cast<const f32x4*>(p1 + 4);
    }
    __syncthreads();   // full drain: B(0),B(1),A(0) ready

    f32x4 acc[4][4];
    #pragma unroll
    for (int m = 0; m < 4; ++m)
        #pragma unroll
        for (int n = 0; n < 4; ++n) acc[m][n] = (f32x4){0.f, 0.f, 0.f, 0.f};

    f32x4 aregb[2];   // second halves for in-loop prefetch
    aregb[1] = areg1b;

    // ---------------- pipelined K loop ----------------
    #pragma unroll
    for (int ks = 0; ks < NKS; ++ks) {
        if (is_consumer) {
            // ---- pure compute: 4 A reads + 4 B reads + 16 MFMA ----
            char* Ard = smem + (ks & 1) * 4096;
            const char* Brd = smem + 8192 + (ks % 3) * 32768;
            bf16x8 afrag[4];
            #pragma unroll
            for (int m = 0; m < 4; ++m)
                afrag[m] = *reinterpret_cast<const bf16x8*>(Ard + arbyte[m]);
            #pragma unroll
            for (int n = 0; n < 4; ++n) {
                bf16x8 bfrag = *reinterpret_cast<const bf16x8*>(Brd + brbase + n * 256);
                #pragma unroll
                for (int m = 0; m < 4; ++m)
                    acc[m][n] = __builtin_amdgcn_mfma_f32_16x16x32_bf16(afrag[m], bfrag, acc[m][n], 0, 0, 0);
            }
        } else {
            // ---- producers: issue stages for ks+2, write A(ks+1) ----
            if (ks + 2 <= NKS - 1) {
                char* bdst = smem + 8192 + ((ks + 2) % 3) * 32768;
                const __bf16* src = Vsall + (size_t)(ks + 2) * 16384;
                #pragma unroll
                for (int i = 0; i < 8; ++i) {
                    int u = i * 256 + ptid;
                    async16(src + (size_t)u * 8, bdst + u * 16);
                }
                if (ks + 2 < NKS - 1) {
                    const float* p = encb + (size_t)arow * H_ + (ks + 2) * 32 + akq * 8;
                    areg[ks & 1]  = *reinterpret_cast<const f32x4*>(p);
                    aregb[ks & 1] = *reinterpret_cast<const f32x4*>(p + 4);
                } else {   // ks == 14: conv inputs for A(16)
                    int t = t0 + arow;
                    int tm = (t > 0) ? t - 1 : 0;
                    int tp = (t + 1 < T_) ? t + 1 : T_ - 1;
                    cx0 = align[(size_t)b * T_ + tm];
                    cx1 = align[(size_t)b * T_ + t];
                    cx2 = align[(size_t)b * T_ + tp];
                    if (t == 0) cx0 = 0.f;
                    if (t + 1 == T_) cx2 = 0.f;
                }
            }
            // write A(ks+1)
            if (ks + 1 <= NKS - 1) {
                bf16x8 v;
                if (ks + 1 < NKS - 1) {
                    f32x4 lo = areg[(ks + 1) & 1];
                    f32x4 hi = aregb[(ks + 1) & 1];
                    v[0]=(__bf16)lo.x; v[1]=(__bf16)lo.y; v[2]=(__bf16)lo.z; v[3]=(__bf16)lo.w;
                    v[4]=(__bf16)hi.x; v[5]=(__bf16)hi.y; v[6]=(__bf16)hi.z; v[7]=(__bf16)hi.w;
                } else {   // A(16) = conv_feat k-extension
                    #pragma unroll
                    for (int e = 0; e < 8; ++e) {
                        int c = akq * 8 + e;
                        v[e] = (__bf16)(conv_b[c] + conv_w[c * 3] * cx0
                                      + conv_w[c * 3 + 1] * cx1 + conv_w[c * 3 + 2] * cx2);
                    }
                }
                char* Adst = smem + ((ks + 1) & 1) * 4096;
                *reinterpret_cast<bf16x8*>(Adst + ag * 16) = v;
            }
            // counted drain: guarantee B(ks+1)/A(ks+1) inputs from iter ks-1 retired,
            // and this iter's ds_writes visible. Never vmcnt(0) in steady state.
            if (ks < 14) {
                asm volatile("s_waitcnt vmcnt(10) lgkmcnt(0)" ::: "memory");
            } else if (ks == 14) {
                asm volatile("s_waitcnt vmcnt(11) lgkmcnt(0)" ::: "memory");
            } else {
                asm volatile("s_waitcnt vmcnt(0) lgkmcnt(0)" ::: "memory");
            }
            __builtin_amdgcn_sched_barrier(0);
        }
        __builtin_amdgcn_s_barrier();
    }
    __syncthreads();   // full drain; spart (aliases A buffers) safe below

    // ---- epilogue (consumers only): tanh(acc + dpb)*w, reduce over 64 cols ----
    if (is_consumer) {
        float dval[4], wv[4];
        #pragma unroll
        for (int n = 0; n < 4; ++n) {
            int a = wid * 64 + n * 16 + row0;
            dval[n] = dpb[b * A_ + a];
            wv[n]   = wvec[a];
        }
        #pragma unroll
        for (int m = 0; m < 4; ++m) {
            float rs[4] = {0.f, 0.f, 0.f, 0.f};
            #pragma unroll
            for (int n = 0; n < 4; ++n) {
                #pragma unroll
                for (int j = 0; j < 4; ++j) {
                    float x = acc[m][n][j] + dval[n];
                    rs[j] += fast_tanh(x) * wv[n];
                }
            }
            #pragma unroll
            for (int j = 0; j < 4; ++j) {
                float v = rs[j];
                v += __shfl_xor(v, 1);
                v += __shfl_xor(v, 2);
                v += __shfl_xor(v, 4);
                v += __shfl_xor(v, 8);
                if (row0 == 0) spart[wid * TT + m * 16 + kg * 4 + j] = v;
            }
        }
    }
    __syncthreads();
    if (tid < TT) {
        float s = 0.f;
        #pragma unroll
        for (int w = 0; w < 8; ++w) s += spart[w * TT + tid];
        scores[b * T_ + t0 + tid] = s;
    }
}

// ---------------- softmax over T per batch; fp32 alignment into d_out ----------------
__global__ __launch_bounds__(256) void softmax_k(
    const float* __restrict__ scores, float* __restrict__ out_align) {
    int b = blockIdx.x;
    int tid = threadIdx.x;
    __shared__ float redm[4];
    __shared__ float reds[4];
    float local[16];
    float mx = -1e30f;
    #pragma unroll
    for (int i = 0; i < 16; ++i) {
        float s = scores[b * T_ + tid + i * 256];
        local[i] = s;
        mx = fmaxf(mx, s);
    }
    for (int off = 32; off >= 1; off >>= 1) mx = fmaxf(mx, __shfl_xor(mx, off));
    if ((tid & 63) == 0) redm[tid >> 6] = mx;
    __syncthreads();
    mx = fmaxf(fmaxf(redm[0], redm[1]), fmaxf(redm[2], redm[3]));
    float sum = 0.f;
    #pragma unroll
    for (int i = 0; i < 16; ++i) { local[i] = __expf(local[i] - mx); sum += local[i]; }
    for (int off = 32; off >= 1; off >>= 1) sum += __shfl_xor(sum, off);
    if ((tid & 63) == 0) reds[tid >> 6] = sum;
    __syncthreads();
    sum = reds[0] + reds[1] + reds[2] + reds[3];
    float inv = 1.0f / sum;
    #pragma unroll
    for (int i = 0; i < 16; ++i)
        out_align[b * T_ + tid + i * 256] = local[i] * inv;
}

// ---------------- pout[b,chunk,h] = sum_{t in chunk} alpha * enc ----------------
__global__ __launch_bounds__(512) void pout_k(
    const float* __restrict__ enc, const float* __restrict__ alpha,
    float* __restrict__ pout) {
    int chunk = blockIdx.x;   // 0..7 (512 rows each)
    int b = blockIdx.y;
    int tid = threadIdx.x;
    int t0 = chunk * 512;
    __shared__ float as[512];
    as[tid] = alpha[b * T_ + t0 + tid];
    __syncthreads();
    float acc = 0.f;
    const float* ep = enc + ((size_t)b * T_ + t0) * H_ + tid;
    #pragma unroll 4
    for (int t = 0; t < 512; ++t) acc += as[t] * ep[(size_t)t * H_];
    pout[((size_t)b * 8 + chunk) * H_ + tid] = acc;
}

__global__ __launch_bounds__(512) void combine_k(
    const float* __restrict__ pout, float* __restrict__ out) {
    int b = blockIdx.x; int h = threadIdx.x;
    float s = 0.f;
    #pragma unroll
    for (int c = 0; c < 8; ++c) s += pout[((size_t)b * 8 + c) * H_ + h];
    out[b * H_ + h] = s;
}

extern "C" void kernel_launch(void* const* d_in, const int* in_sizes, int n_in,
                              void* d_out, int out_size, void* d_ws, size_t ws_size,
                              hipStream_t stream) {
    const float* dec    = (const float*)d_in[0];
    const float* enc    = (const float*)d_in[1];
    const float* align  = (const float*)d_in[2];
    const float* conv_w = (const float*)d_in[3];
    const float* conv_b = (const float*)d_in[4];
    const float* W      = (const float*)d_in[5];
    const float* V      = (const float*)d_in[6];
    const float* U      = (const float*)d_in[7];
    const float* bvec   = (const float*)d_in[8];
    const float* wvec   = (const float*)d_in[9];
    float* out       = (float*)d_out;           // output[B,H] fp32
    float* out_align = out + B_ * H_;           // alignment[B,T] fp32

    char* ws = (char*)d_ws;
    float*  dpb    = (float*)(ws);                   // 64 KB
    float*  scores = (float*)(ws + (64 << 10));      // 512 KB
    float*  pout   = (float*)(ws + (576 << 10));     // 512 KB
    __bf16* Vsall  = (__bf16*)(ws + (1088 << 10));   // 544 KB

    prep_kernel<<<(B_ * A_ + A_ * H_ + A_ * C_) / 256, 256, 0, stream>>>(
        dec, W, bvec, V, U, dpb, Vsall);
    scores_mfma<<<dim3(T_ / TT, B_), 768, 0, stream>>>(enc, align, conv_w, conv_b,
                                                       Vsall, dpb, wvec, scores);
    softmax_k<<<B_, 256, 0, stream>>>(scores, out_align);
    pout_k<<<dim3(8, B_), 512, 0, stream>>>(enc, out_align, pout);
    combine_k<<<B_, 512, 0, stream>>>(pout, out);
}

// Round 14
// 166.948 us; speedup vs baseline: 2.2810x; 1.3805x over previous
//
#include <hip/hip_runtime.h>
#include <hip/hip_bf16.h>

#define B_ 32
#define T_ 4096
#define H_ 512
#define A_ 512
#define C_ 32
#define KTOT 544            // H + C (conv folded in as K-extension)
#define NKS  (KTOT / 32)    // 17 MFMA k-steps
#define TT   64             // t-tile rows per block
#define NCH  (T_ / TT)      // 64 t-chunks per batch

typedef float f32x4 __attribute__((ext_vector_type(4)));
typedef __bf16 bf16x8 __attribute__((ext_vector_type(8)));

__device__ inline float fast_tanh(float x) {
    // tanh(x) = 1 - 2/(exp(2x)+1); exact at saturation, |err| ~1e-7
    float t = __expf(2.0f * x);
    return 1.0f - 2.0f / (t + 1.0f);
}

__device__ __forceinline__ void async16(const void* g, void* l) {
    __builtin_amdgcn_global_load_lds(
        (const __attribute__((address_space(1))) unsigned int*)g,
        (__attribute__((address_space(3))) unsigned int*)l, 16, 0, 0);
}

// ---------------- prep: dpb = dec@W^T + b ; V,U -> unified bf16 fragment buffer ----
// Vsall[(k>>3)*A + a]*8 + (k&7), k in [0,544). Per-kstep 32KB chunk contiguous.
__global__ __launch_bounds__(256) void prep_kernel(
    const float* __restrict__ dec, const float* __restrict__ W,
    const float* __restrict__ bvec, const float* __restrict__ V,
    const float* __restrict__ U,
    float* __restrict__ dpb, __bf16* __restrict__ Vsall) {
    int id = blockIdx.x * 256 + threadIdx.x;
    const int N1 = B_ * A_;          // 16384
    const int N2 = A_ * H_;          // 262144
    if (id < N1) {
        int b = id / A_, a = id % A_;
        const float* dr = dec + b * H_;
        const float* wr = W + (size_t)a * H_;
        float s = 0.f;
        #pragma unroll 8
        for (int h = 0; h < H_; ++h) s += dr[h] * wr[h];
        dpb[id] = s + bvec[a];
    } else if (id < N1 + N2) {
        int e = id - N1;
        int a = e >> 9, k = e & 511;
        Vsall[((k >> 3) * A_ + a) * 8 + (k & 7)] = (__bf16)V[(size_t)a * H_ + k];
    } else {
        int e = id - N1 - N2;        // 16384 U elements
        int a = e >> 5, c = e & 31;
        int k = H_ + c;
        Vsall[((k >> 3) * A_ + a) * 8 + (k & 7)] = (__bf16)U[a * C_ + c];
    }
}

// ---------------- fused scores + flash-style output partials ----------------
// r8 structure: 64x512 tile, dual-dbuf, 8 waves. After scores, computes
// m_c, l_c, u_c[h] = sum_t exp(s_t - m_c) * enc[t][h] (enc tile L2-hot).
__global__ __launch_bounds__(512) void scores_mfma(
    const float* __restrict__ enc, const float* __restrict__ align,
    const float* __restrict__ conv_w, const float* __restrict__ conv_b,
    const __bf16* __restrict__ Vsall, const float* __restrict__ dpb,
    const float* __restrict__ wvec, float* __restrict__ scores,
    float* __restrict__ ml_buf, float* __restrict__ u_buf) {
    const int bx = blockIdx.x;
    const int t0 = bx * TT;
    const int b  = blockIdx.y;
    const int tid = threadIdx.x;
    const int lane = tid & 63, wid = tid >> 6;
    const int row0 = lane & 15;   // C/D col lane
    const int kg   = lane >> 4;   // k-group 0..3 within the 32-k step
    const int wq   = wid & 3;     // col quarter
    const int wr   = wid >> 2;    // row half (32 rows)
    const int wcol = wq * 128;

    __shared__ char smem[73728];  // A dbuf 2x4KB @0, B dbuf 2x32KB @8192
    float* spart = (float*)smem;  // [4][TT] = 1KB, aliases A after the loop
    float* eL    = (float*)(smem + 2048);   // [TT] exp values (aliases A buf 1)
    float* mbox  = (float*)(smem + 2560);

    const float* encb = enc + ((size_t)b * T_ + t0) * H_;
    const int arow = tid >> 2, akgl = tid & 3;   // A staging assignment (tid<256)

    // ---- stage kstep 0 ----
    {
        __bf16* bdst = (__bf16*)(smem + 8192);
        #pragma unroll
        for (int i = 0; i < 4; ++i) {
            int u = i * 512 + tid;
            async16(Vsall + u * 8, bdst + u * 8);
        }
    }
    if (tid < 256) {
        const float* p = encb + arow * H_ + akgl * 8;
        f32x4 lo = *reinterpret_cast<const f32x4*>(p);
        f32x4 hi = *reinterpret_cast<const f32x4*>(p + 4);
        bf16x8 v;
        v[0] = (__bf16)lo.x; v[1] = (__bf16)lo.y; v[2] = (__bf16)lo.z; v[3] = (__bf16)lo.w;
        v[4] = (__bf16)hi.x; v[5] = (__bf16)hi.y; v[6] = (__bf16)hi.z; v[7] = (__bf16)hi.w;
        int g = tid ^ ((tid >> 4) & 7);
        *reinterpret_cast<bf16x8*>((__bf16*)smem + g * 8) = v;
    }
    __syncthreads();

    f32x4 acc[2][8];
    #pragma unroll
    for (int m = 0; m < 2; ++m)
        #pragma unroll
        for (int n = 0; n < 8; ++n) acc[m][n] = (f32x4){0.f, 0.f, 0.f, 0.f};

    int cur = 0;
    for (int ks = 0; ks < NKS; ++ks) {
        __bf16* Acur = (__bf16*)(smem + (cur ? 4096 : 0));
        __bf16* Anxt = (__bf16*)(smem + (cur ? 0 : 4096));
        __bf16* Bcur = (__bf16*)(smem + 8192 + (cur ? 32768 : 0));
        __bf16* Bnxt = (__bf16*)(smem + 8192 + (cur ? 0 : 32768));

        f32x4 alo, ahi;
        bool stage = (ks + 1 < NKS);
        bool conv_step = (ks + 1 == NKS - 1);
        if (stage) {
            const __bf16* vchunk = Vsall + (size_t)(ks + 1) * (4 * A_ * 8);
            #pragma unroll
            for (int i = 0; i < 4; ++i) {
                int u = i * 512 + tid;
                async16(vchunk + u * 8, Bnxt + u * 8);
            }
            if (tid < 256 && !conv_step) {
                const float* p = encb + arow * H_ + (ks + 1) * 32 + akgl * 8;
                alo = *reinterpret_cast<const f32x4*>(p);
                ahi = *reinterpret_cast<const f32x4*>(p + 4);
            }
        }

        // ---- compute current k-step ----
        bf16x8 afrag[2];
        #pragma unroll
        for (int m = 0; m < 2; ++m) {
            int row = wr * 32 + m * 16 + row0;
            int u = row * 4 + kg;
            int g = u ^ ((u >> 4) & 7);
            afrag[m] = *reinterpret_cast<const bf16x8*>(Acur + g * 8);
        }
        const __bf16* bp = Bcur + kg * (A_ * 8);
        #pragma unroll
        for (int n = 0; n < 8; ++n) {
            bf16x8 bfrag = *reinterpret_cast<const bf16x8*>(bp + (wcol + n * 16 + row0) * 8);
            acc[0][n] = __builtin_amdgcn_mfma_f32_16x16x32_bf16(afrag[0], bfrag, acc[0][n], 0, 0, 0);
            acc[1][n] = __builtin_amdgcn_mfma_f32_16x16x32_bf16(afrag[1], bfrag, acc[1][n], 0, 0, 0);
        }

        // ---- write A-next to LDS ----
        if (stage && tid < 256) {
            bf16x8 v;
            if (!conv_step) {
                v[0] = (__bf16)alo.x; v[1] = (__bf16)alo.y; v[2] = (__bf16)alo.z; v[3] = (__bf16)alo.w;
                v[4] = (__bf16)ahi.x; v[5] = (__bf16)ahi.y; v[6] = (__bf16)ahi.z; v[7] = (__bf16)ahi.w;
            } else {
                int t = t0 + arow;
                float x0 = (t > 0) ? align[b * T_ + t - 1] : 0.f;
                float x1 = align[b * T_ + t];
                float x2 = (t + 1 < T_) ? align[b * T_ + t + 1] : 0.f;
                #pragma unroll
                for (int e = 0; e < 8; ++e) {
                    int c = akgl * 8 + e;
                    v[e] = (__bf16)(conv_b[c] + conv_w[c * 3 + 0] * x0
                                  + conv_w[c * 3 + 1] * x1 + conv_w[c * 3 + 2] * x2);
                }
            }
            int g = tid ^ ((tid >> 4) & 7);
            *reinterpret_cast<bf16x8*>(Anxt + g * 8) = v;
        }
        __syncthreads();
        cur ^= 1;
    }

    // ---- epilogue 1: tanh(acc + dpb)*w, reduce over A -> scores ----
    float dval[8], wv[8];
    #pragma unroll
    for (int n = 0; n < 8; ++n) {
        int a = wcol + n * 16 + row0;
        dval[n] = dpb[b * A_ + a];
        wv[n]   = wvec[a];
    }
    #pragma unroll
    for (int m = 0; m < 2; ++m) {
        float rs[4] = {0.f, 0.f, 0.f, 0.f};
        #pragma unroll
        for (int n = 0; n < 8; ++n) {
            #pragma unroll
            for (int j = 0; j < 4; ++j) {
                float x = acc[m][n][j] + dval[n];
                rs[j] += fast_tanh(x) * wv[n];
            }
        }
        #pragma unroll
        for (int j = 0; j < 4; ++j) {
            float v = rs[j];
            v += __shfl_xor(v, 1);
            v += __shfl_xor(v, 2);
            v += __shfl_xor(v, 4);
            v += __shfl_xor(v, 8);
            if (row0 == 0) spart[wq * TT + wr * 32 + m * 16 + kg * 4 + j] = v;
        }
    }
    __syncthreads();

    // ---- epilogue 2: flash-style chunk partials (m_c, l_c, u_c[h]) ----
    if (tid < TT) {   // wave 0 exactly (TT=64)
        float s = spart[0 * TT + tid] + spart[1 * TT + tid]
                + spart[2 * TT + tid] + spart[3 * TT + tid];
        scores[b * T_ + t0 + tid] = s;
        float mx = s;
        #pragma unroll
        for (int off = 32; off >= 1; off >>= 1) mx = fmaxf(mx, __shfl_xor(mx, off));
        float e = __expf(s - mx);
        eL[tid] = e;
        float l = e;
        #pragma unroll
        for (int off = 32; off >= 1; off >>= 1) l += __shfl_xor(l, off);
        if (tid == 0) {
            mbox[0] = mx;   // (diagnostic; ml_buf is the real carrier)
            ml_buf[((size_t)b * NCH + bx) * 2 + 0] = mx;
            ml_buf[((size_t)b * NCH + bx) * 2 + 1] = l;
        }
    }
    __syncthreads();
    // u[h] = sum_t eL[t] * enc[t][h]; thread = h (512 threads), enc tile L2-hot
    {
        float u0 = 0.f, u1 = 0.f, u2 = 0.f, u3 = 0.f;
        const float* ep = encb + tid;
        #pragma unroll 4
        for (int t = 0; t < TT; t += 4) {
            u0 += eL[t]     * ep[(size_t)t * H_];
            u1 += eL[t + 1] * ep[(size_t)(t + 1) * H_];
            u2 += eL[t + 2] * ep[(size_t)(t + 2) * H_];
            u3 += eL[t + 3] * ep[(size_t)(t + 3) * H_];
        }
        u_buf[((size_t)b * NCH + bx) * H_ + tid] = (u0 + u1) + (u2 + u3);
    }
}

// ---------------- softmax over T per batch; fp32 alignment into d_out ----------------
__global__ __launch_bounds__(256) void softmax_k(
    const float* __restrict__ scores, float* __restrict__ out_align) {
    int b = blockIdx.x;
    int tid = threadIdx.x;
    __shared__ float redm[4];
    __shared__ float reds[4];
    float local[16];
    float mx = -1e30f;
    #pragma unroll
    for (int i = 0; i < 16; ++i) {
        float s = scores[b * T_ + tid + i * 256];
        local[i] = s;
        mx = fmaxf(mx, s);
    }
    for (int off = 32; off >= 1; off >>= 1) mx = fmaxf(mx, __shfl_xor(mx, off));
    if ((tid & 63) == 0) redm[tid >> 6] = mx;
    __syncthreads();
    mx = fmaxf(fmaxf(redm[0], redm[1]), fmaxf(redm[2], redm[3]));
    float sum = 0.f;
    #pragma unroll
    for (int i = 0; i < 16; ++i) { local[i] = __expf(local[i] - mx); sum += local[i]; }
    for (int off = 32; off >= 1; off >>= 1) sum += __shfl_xor(sum, off);
    if ((tid & 63) == 0) reds[tid >> 6] = sum;
    __syncthreads();
    sum = reds[0] + reds[1] + reds[2] + reds[3];
    float inv = 1.0f / sum;
    #pragma unroll
    for (int i = 0; i < 16; ++i)
        out_align[b * T_ + tid + i * 256] = local[i] * inv;
}

// ---------------- combine2: out[b][h] = sum_c w_c u_c[h] / sum_c w_c l_c ----------------
__global__ __launch_bounds__(512) void combine2_k(
    const float* __restrict__ ml_buf, const float* __restrict__ u_buf,
    float* __restrict__ out) {
    int b = blockIdx.x;
    int h = threadIdx.x;
    __shared__ float wsh[NCH];
    __shared__ float dsh[1];
    if (h < NCH) {
        float m = ml_buf[((size_t)b * NCH + h) * 2];
        float mb = m;
        #pragma unroll
        for (int off = 32; off >= 1; off >>= 1) mb = fmaxf(mb, __shfl_xor(mb, off));
        float w = __expf(m - mb);
        wsh[h] = w;
        float d = w * ml_buf[((size_t)b * NCH + h) * 2 + 1];
        #pragma unroll
        for (int off = 32; off >= 1; off >>= 1) d += __shfl_xor(d, off);
        if (h == 0) dsh[0] = d;
    }
    __syncthreads();
    float acc = 0.f;
    #pragma unroll 4
    for (int c = 0; c < NCH; ++c)
        acc += wsh[c] * u_buf[((size_t)b * NCH + c) * H_ + h];
    out[b * H_ + h] = acc / dsh[0];
}

extern "C" void kernel_launch(void* const* d_in, const int* in_sizes, int n_in,
                              void* d_out, int out_size, void* d_ws, size_t ws_size,
                              hipStream_t stream) {
    const float* dec    = (const float*)d_in[0];
    const float* enc    = (const float*)d_in[1];
    const float* align  = (const float*)d_in[2];
    const float* conv_w = (const float*)d_in[3];
    const float* conv_b = (const float*)d_in[4];
    const float* W      = (const float*)d_in[5];
    const float* V      = (const float*)d_in[6];
    const float* U      = (const float*)d_in[7];
    const float* bvec   = (const float*)d_in[8];
    const float* wvec   = (const float*)d_in[9];
    float* out       = (float*)d_out;           // output[B,H] fp32
    float* out_align = out + B_ * H_;           // alignment[B,T] fp32

    char* ws = (char*)d_ws;
    float*  dpb    = (float*)(ws);                   // 64 KB
    float*  scores = (float*)(ws + (64 << 10));      // 512 KB
    float*  ml_buf = (float*)(ws + (576 << 10));     // 32*64*2*4 = 16 KB
    float*  u_buf  = (float*)(ws + (592 << 10));     // 32*64*512*4 = 4 MB
    __bf16* Vsall  = (__bf16*)(ws + (592 << 10) + (4 << 20));   // 544 KB

    prep_kernel<<<(B_ * A_ + A_ * H_ + A_ * C_) / 256, 256, 0, stream>>>(
        dec, W, bvec, V, U, dpb, Vsall);
    scores_mfma<<<dim3(T_ / TT, B_), 512, 0, stream>>>(enc, align, conv_w, conv_b,
                                                       Vsall, dpb, wvec, scores,
                                                       ml_buf, u_buf);
    softmax_k<<<B_, 256, 0, stream>>>(scores, out_align);
    combine2_k<<<B_, 512, 0, stream>>>(ml_buf, u_buf, out);
}